// Round 1
// baseline (344.491 us; speedup 1.0000x reference)
//
#include <hip/hip_runtime.h>

// ---------------------------------------------------------------------------
// GCN + MHA + gated fuse + LayerNorm, MI355X (gfx950).
// All matmul-shaped work in bf16 MFMA (16x16x32), fp32 accumulate.
// ---------------------------------------------------------------------------

typedef __attribute__((ext_vector_type(8))) short b16x8;   // 8 bf16 = 4 VGPRs
typedef __attribute__((ext_vector_type(4))) float f32x4;

constexpr int N  = 1024;
constexpr int B  = 8;
constexpr int D  = 768;
constexpr int H  = 8;
constexpr int DH = 96;
constexpr int E  = 16384;
constexpr int M  = N * B;          // 8192 rows, row r = n*B + b
constexpr float LN_EPS = 1e-5f;

#define DEV static __device__ __forceinline__

DEV unsigned short f2b(float f) {           // f32 -> bf16 RNE
  unsigned u = __float_as_uint(f);
  u += 0x7fffu + ((u >> 16) & 1u);
  return (unsigned short)(u >> 16);
}
DEV float b2f(unsigned short h) { return __uint_as_float(((unsigned)h) << 16); }

// ---------------------------------------------------------------------------
// small utility kernels
// ---------------------------------------------------------------------------
__global__ void cast_f2b_kernel(const float* __restrict__ in,
                                unsigned short* __restrict__ out, int n4) {
  int i = blockIdx.x * 256 + threadIdx.x;
  if (i < n4) {
    float4 v = ((const float4*)in)[i];
    ushort4 o;
    o.x = f2b(v.x); o.y = f2b(v.y); o.z = f2b(v.z); o.w = f2b(v.w);
    ((ushort4*)out)[i] = o;
  }
}

__global__ void zero_i32_kernel(int* __restrict__ p, int n) {
  int i = blockIdx.x * 256 + threadIdx.x;
  if (i < n) p[i] = 0;
}

// count in-degree per (b, dst). edge_index layout [B,2,E].
__global__ void edge_count_kernel(const int* __restrict__ ei, int* __restrict__ cnt) {
  int i = blockIdx.x * 256 + threadIdx.x;      // B*E threads exactly
  int b = i >> 14, e = i & (E - 1);
  int dst = ei[(b << 15) + E + e];
  atomicAdd(&cnt[(b << 10) + dst], 1);
}

// per-batch exclusive scan of counts (1024 entries) + dinv = rsqrt(1+cnt)
__global__ __launch_bounds__(1024) void scan_offs_kernel(
    const int* __restrict__ cnt, int* __restrict__ offs,
    int* __restrict__ cursor, float* __restrict__ dinv) {
  __shared__ int buf[1024];
  const int b = blockIdx.x, i = threadIdx.x, g = (b << 10) + i;
  const int c = cnt[g];
  buf[i] = c;
  __syncthreads();
  for (int off = 1; off < 1024; off <<= 1) {
    int t = (i >= off) ? buf[i - off] : 0;
    __syncthreads();
    buf[i] += t;
    __syncthreads();
  }
  const int excl = buf[i] - c;
  offs[g] = excl;
  cursor[g] = excl;
  dinv[g] = rsqrtf((float)(c + 1));           // self-loop included
}

__global__ void edge_fill_kernel(const int* __restrict__ ei,
                                 int* __restrict__ cursor, int* __restrict__ elist) {
  int i = blockIdx.x * 256 + threadIdx.x;
  int b = i >> 14, e = i & (E - 1);
  int dst = ei[(b << 15) + E + e];
  int slot = atomicAdd(&cursor[(b << 10) + dst], 1);
  elist[(b << 14) + slot] = e;
}

// ---------------------------------------------------------------------------
// bf16 MFMA GEMM:  C[M x Ncol] = A[M x K] @ W[Ncol x K]^T (+ bias)
// BM=128 BN=64 BK=32, 256 threads (4 waves, 2x2), each wave 64x32.
// LDS padded to 40 cols -> conflict-free ds_read_b128 fragments.
// ---------------------------------------------------------------------------
constexpr int EPI_H    = 0;   // -> h bf16 [B,N,D]
constexpr int EPI_QKV  = 1;   // -> q,k [B,H,N,DH] bf16 ; v [B,H,DH,N] bf16
constexpr int EPI_ATTN = 2;   // -> attn f32 [r,c] ; cat bf16 [r, 768+c]
constexpr int EPI_GATE = 3;   // -> sigmoid -> gate f32 [r,c]

template <int EPI>
__global__ __launch_bounds__(256) void gemm_bt(
    const unsigned short* __restrict__ A, const unsigned short* __restrict__ W,
    const float* __restrict__ bias, int K,
    void* __restrict__ p0, void* __restrict__ p1, void* __restrict__ p2) {
  __shared__ __align__(16) unsigned short sA[128][40];
  __shared__ __align__(16) unsigned short sB[64][40];
  const int tid = threadIdx.x;
  const int lane = tid & 63, wid = tid >> 6;
  const int wm = wid >> 1, wn = wid & 1;
  const int m0 = blockIdx.y * 128, n0 = blockIdx.x * 64;
  const int l15 = lane & 15, lhi = lane >> 4;

  f32x4 acc[4][2] = {};

  const int ar0 = tid >> 2, ac0 = (tid & 3) * 8;  // A chunk0: rows 0..63
  const int ar1 = ar0 + 64;                       // A chunk1: rows 64..127
  const int br = tid >> 2, bc = (tid & 3) * 8;

  uint4 ra0, ra1, rb;
  auto ld = [&](int kt) {
    ra0 = *(const uint4*)(A + ((size_t)(m0 + ar0) * K + kt * 32 + ac0));
    ra1 = *(const uint4*)(A + ((size_t)(m0 + ar1) * K + kt * 32 + ac0));
    rb  = *(const uint4*)(W + ((size_t)(n0 + br)  * K + kt * 32 + bc));
  };
  ld(0);
  const int NT = K >> 5;
  for (int kt = 0; kt < NT; ++kt) {
    __syncthreads();
    *(uint4*)&sA[ar0][ac0] = ra0;
    *(uint4*)&sA[ar1][ac0] = ra1;
    *(uint4*)&sB[br][bc] = rb;
    __syncthreads();
    if (kt + 1 < NT) ld(kt + 1);   // prefetch overlaps MFMA
    b16x8 af[4], bfr[2];
#pragma unroll
    for (int i = 0; i < 4; ++i)
      af[i] = *(const b16x8*)&sA[wm * 64 + i * 16 + l15][lhi * 8];
#pragma unroll
    for (int j = 0; j < 2; ++j)
      bfr[j] = *(const b16x8*)&sB[wn * 32 + j * 16 + l15][lhi * 8];
#pragma unroll
    for (int i = 0; i < 4; ++i)
#pragma unroll
      for (int j = 0; j < 2; ++j)
        acc[i][j] = __builtin_amdgcn_mfma_f32_16x16x32_bf16(af[i], bfr[j], acc[i][j], 0, 0, 0);
  }

  // epilogue: C/D layout col = lane&15, row = (lane>>4)*4 + reg  [HW-verified]
#pragma unroll
  for (int i = 0; i < 4; ++i) {
#pragma unroll
    for (int j = 0; j < 2; ++j) {
      const int c = n0 + wn * 32 + j * 16 + l15;
      const float bv = bias ? bias[c] : 0.0f;
#pragma unroll
      for (int g = 0; g < 4; ++g) {
        const int r = m0 + wm * 64 + i * 16 + lhi * 4 + g;
        float v = acc[i][j][g] + bv;
        if constexpr (EPI == EPI_H) {
          const int n = r >> 3, b = r & 7;
          ((unsigned short*)p0)[((size_t)((b << 10) + n)) * 768 + c] = f2b(v);
        } else if constexpr (EPI == EPI_QKV) {
          const int n = r >> 3, b = r & 7;
          const int sec = c / 768, cc = c - sec * 768;
          const int hd = cc / 96, dh = cc - hd * 96;
          unsigned short* dst =
              (sec == 0) ? (unsigned short*)p0
                         : (sec == 1 ? (unsigned short*)p1 : (unsigned short*)p2);
          size_t idx;
          if (sec < 2) idx = ((size_t)((b * 8 + hd) * 1024 + n)) * 96 + dh;   // [B,H,N,DH]
          else         idx = ((size_t)((b * 8 + hd) * 96 + dh)) * 1024 + n;   // V^T [B,H,DH,N]
          dst[idx] = f2b(v);
        } else if constexpr (EPI == EPI_ATTN) {
          ((float*)p1)[(size_t)r * 768 + c] = v;
          ((unsigned short*)p0)[(size_t)r * 1536 + 768 + c] = f2b(v);
        } else {  // EPI_GATE
          ((float*)p1)[(size_t)r * 768 + c] = 1.0f / (1.0f + __expf(-v));
        }
      }
    }
  }
}

// ---------------------------------------------------------------------------
// flash-style attention. block = (q-tile of 64 rows, bh). 4 waves x 16 q-rows.
// ---------------------------------------------------------------------------
__global__ __launch_bounds__(256) void attn_kernel(
    const unsigned short* __restrict__ qb, const unsigned short* __restrict__ kb,
    const unsigned short* __restrict__ vb, unsigned short* __restrict__ ctx) {
  __shared__ __align__(16) unsigned short sK[64][104];  // [key][dh], pad 96->104
  __shared__ __align__(16) unsigned short sV[96][72];   // [dh][key], pad 64->72
  __shared__ __align__(16) unsigned short sP[4][16][72];
  const int tid = threadIdx.x, lane = tid & 63, wid = tid >> 6;
  const int l15 = lane & 15, lhi = lane >> 4;
  const int bh = blockIdx.y, q0 = blockIdx.x * 64;
  const float SCL = 0.14724445f;  // (1/sqrt(96)) * log2(e)

  // Q fragments in registers (rows q0+wid*16+l15, dh = ks*32 + lhi*8 + j)
  b16x8 qf[3];
  const size_t qbase = ((size_t)bh * 1024 + q0 + wid * 16 + l15) * 96 + lhi * 8;
#pragma unroll
  for (int ks = 0; ks < 3; ++ks) qf[ks] = *(const b16x8*)(qb + qbase + ks * 32);

  f32x4 accO[6] = {};
  float mprev[4] = {-1e30f, -1e30f, -1e30f, -1e30f};
  float ssum[4] = {0.f, 0.f, 0.f, 0.f};

  for (int kt = 0; kt < 16; ++kt) {
    __syncthreads();  // previous iteration's reads of sK/sV done
#pragma unroll
    for (int p = 0; p < 3; ++p) {
      int chunk = p * 256 + tid;                 // 768 x 16B chunks each
      int row = chunk / 12, c8 = chunk % 12;     // K tile [64][96]
      *(uint4*)&sK[row][c8 * 8] =
          *(const uint4*)(kb + ((size_t)bh * 1024 + kt * 64 + row) * 96 + c8 * 8);
      int rv = chunk >> 3, cv = chunk & 7;       // V^T tile [96][64]
      *(uint4*)&sV[rv][cv * 8] =
          *(const uint4*)(vb + ((size_t)bh * 96 + rv) * 1024 + kt * 64 + cv * 8);
    }
    __syncthreads();

    // S = Q K^T  (wave: 16 q-rows x 64 keys)
    f32x4 sf[4] = {};
#pragma unroll
    for (int f = 0; f < 4; ++f) {
#pragma unroll
      for (int ks = 0; ks < 3; ++ks) {
        b16x8 kf = *(const b16x8*)&sK[f * 16 + l15][ks * 32 + lhi * 8];
        sf[f] = __builtin_amdgcn_mfma_f32_16x16x32_bf16(qf[ks], kf, sf[f], 0, 0, 0);
      }
    }

    // online softmax; S row = lhi*4+g lives in 16-lane group lhi
#pragma unroll
    for (int g = 0; g < 4; ++g) {
      float rmax = fmaxf(fmaxf(sf[0][g], sf[1][g]), fmaxf(sf[2][g], sf[3][g]));
#pragma unroll
      for (int msk = 1; msk < 16; msk <<= 1) rmax = fmaxf(rmax, __shfl_xor(rmax, msk));
      const float mnew = fmaxf(mprev[g], rmax);
      const float alpha = exp2f((mprev[g] - mnew) * SCL);
      float rs = 0.f;
#pragma unroll
      for (int f = 0; f < 4; ++f) {
        float pv = exp2f((sf[f][g] - mnew) * SCL);
        sP[wid][lhi * 4 + g][f * 16 + l15] = f2b(pv);
        rs += pv;
      }
#pragma unroll
      for (int msk = 1; msk < 16; msk <<= 1) rs += __shfl_xor(rs, msk);
      ssum[g] = ssum[g] * alpha + rs;
      mprev[g] = mnew;
#pragma unroll
      for (int o = 0; o < 6; ++o) accO[o][g] *= alpha;
    }

    // O += P V   (per-wave sP; in-wave LDS ordering suffices)
#pragma unroll
    for (int ks = 0; ks < 2; ++ks) {
      b16x8 pa = *(const b16x8*)&sP[wid][l15][ks * 32 + lhi * 8];
#pragma unroll
      for (int o = 0; o < 6; ++o) {
        b16x8 vf = *(const b16x8*)&sV[o * 16 + l15][ks * 32 + lhi * 8];
        accO[o] = __builtin_amdgcn_mfma_f32_16x16x32_bf16(pa, vf, accO[o], 0, 0, 0);
      }
    }
  }

  const int b = bh >> 3, hd = bh & 7;
  float rinv[4];
#pragma unroll
  for (int g = 0; g < 4; ++g) rinv[g] = 1.0f / ssum[g];
#pragma unroll
  for (int o = 0; o < 6; ++o)
#pragma unroll
    for (int g = 0; g < 4; ++g) {
      const int qrow = q0 + wid * 16 + lhi * 4 + g;
      ctx[((size_t)qrow * 8 + b) * 768 + hd * 96 + o * 16 + l15] =
          f2b(accO[o][g] * rinv[g]);
    }
}

// ---------------------------------------------------------------------------
// GCN aggregation: block per (b,n); gather CSR in-edges + self loop + bias.
// ---------------------------------------------------------------------------
__global__ __launch_bounds__(256) void gcn_agg_kernel(
    const unsigned short* __restrict__ h16, const int* __restrict__ ei,
    const int* __restrict__ cnt, const int* __restrict__ offs,
    const int* __restrict__ elist, const float* __restrict__ dinv,
    const float* __restrict__ gcn_b, float* __restrict__ gcn_f32,
    unsigned short* __restrict__ cat16) {
  const int bn = blockIdx.x;  // b*1024 + n
  const int b = bn >> 10, n = bn & 1023;
  const int t = threadIdx.x;
  const float dn = dinv[bn];
  const size_t hrow = (size_t)bn * 768;
  float acc[3];
#pragma unroll
  for (int j = 0; j < 3; ++j) acc[j] = dn * dn * b2f(h16[hrow + t + 256 * j]);
  const int st = offs[bn], cv = cnt[bn];
  for (int i = 0; i < cv; ++i) {
    const int e = elist[(b << 14) + st + i];
    const int src = ei[(b << 15) + e];
    const float nv = dinv[(b << 10) + src] * dn;
    const size_t srow = (size_t)((b << 10) + src) * 768;
#pragma unroll
    for (int j = 0; j < 3; ++j) acc[j] += nv * b2f(h16[srow + t + 256 * j]);
  }
  const size_t crow = ((size_t)n * 8 + b) * 1536;
#pragma unroll
  for (int j = 0; j < 3; ++j) {
    const int d = t + 256 * j;
    const float v = acc[j] + gcn_b[d];
    gcn_f32[hrow + d] = v;
    cat16[crow + d] = f2b(v);
  }
}

// ---------------------------------------------------------------------------
// gate-blend + residual + LayerNorm. block per row r = n*8+b.
// ---------------------------------------------------------------------------
__global__ __launch_bounds__(256) void ln_fuse_kernel(
    const float* __restrict__ gate, const float* __restrict__ gcn,
    const float* __restrict__ attn, const float* __restrict__ x,
    const float* __restrict__ lng, const float* __restrict__ lnb,
    float* __restrict__ out) {
  const int r = blockIdx.x;
  const int t = threadIdx.x, lane = t & 63, wid = t >> 6;
  const int b = r & 7, n = r >> 3;
  const size_t xrow = (size_t)r * 768;
  const size_t grow = (size_t)((b << 10) + n) * 768;
  float f[3], s1 = 0.f, s2 = 0.f;
#pragma unroll
  for (int j = 0; j < 3; ++j) {
    const int d = t + 256 * j;
    const float gv = gate[xrow + d];
    const float fv = gv * gcn[grow + d] + (1.f - gv) * attn[xrow + d] + x[xrow + d];
    f[j] = fv; s1 += fv; s2 += fv * fv;
  }
#pragma unroll
  for (int msk = 1; msk < 64; msk <<= 1) {
    s1 += __shfl_xor(s1, msk);
    s2 += __shfl_xor(s2, msk);
  }
  __shared__ float p1[4], p2[4];
  if (lane == 0) { p1[wid] = s1; p2[wid] = s2; }
  __syncthreads();
  s1 = p1[0] + p1[1] + p1[2] + p1[3];
  s2 = p2[0] + p2[1] + p2[2] + p2[3];
  const float mu = s1 * (1.f / 768.f);
  float var = s2 * (1.f / 768.f) - mu * mu;
  var = fmaxf(var, 0.f);
  const float rstd = rsqrtf(var + LN_EPS);
#pragma unroll
  for (int j = 0; j < 3; ++j) {
    const int d = t + 256 * j;
    out[xrow + d] = (f[j] - mu) * rstd * lng[d] + lnb[d];
  }
}

// ---------------------------------------------------------------------------
extern "C" void kernel_launch(void* const* d_in, const int* in_sizes, int n_in,
                              void* d_out, int out_size, void* d_ws, size_t ws_size,
                              hipStream_t stream) {
  const float* x     = (const float*)d_in[0];
  const int*   ei    = (const int*)d_in[1];
  const float* gcnW  = (const float*)d_in[2];
  const float* gcnb  = (const float*)d_in[3];
  const float* ipw   = (const float*)d_in[4];
  const float* ipb   = (const float*)d_in[5];
  const float* opw   = (const float*)d_in[6];
  const float* opb   = (const float*)d_in[7];
  const float* gw    = (const float*)d_in[8];
  const float* gb    = (const float*)d_in[9];
  const float* lng   = (const float*)d_in[10];
  const float* lnb   = (const float*)d_in[11];
  float* out = (float*)d_out;

  char* p = (char*)d_ws;
  auto alloc = [&](size_t bytes) { void* q = p; p += (bytes + 255) & ~(size_t)255; return q; };

  unsigned short* xb16  = (unsigned short*)alloc((size_t)M * 768 * 2);   // also ctx16
  unsigned short* wqkv  = (unsigned short*)alloc((size_t)2304 * 768 * 2);
  unsigned short* wgcn  = (unsigned short*)alloc((size_t)768 * 768 * 2);
  unsigned short* wout  = (unsigned short*)alloc((size_t)768 * 768 * 2);
  unsigned short* wgate = (unsigned short*)alloc((size_t)768 * 1536 * 2);
  unsigned short* qb    = (unsigned short*)alloc((size_t)B * H * N * DH * 2); // also gatef (w/ kb)
  unsigned short* kb    = (unsigned short*)alloc((size_t)B * H * N * DH * 2);
  unsigned short* vb    = (unsigned short*)alloc((size_t)B * H * DH * N * 2); // also attnf (w/ h16)
  unsigned short* h16   = (unsigned short*)alloc((size_t)M * 768 * 2);
  unsigned short* cat16 = (unsigned short*)alloc((size_t)M * 1536 * 2);
  float* gcnf           = (float*)alloc((size_t)M * 768 * 4);
  int* cnt    = (int*)alloc(8192 * 4);
  int* offs   = (int*)alloc(8192 * 4);
  int* cursor = (int*)alloc(8192 * 4);
  float* dinv = (float*)alloc(8192 * 4);
  int* elist  = (int*)alloc((size_t)B * E * 4);

  // safe aliases (serial-stream ordering makes these race-free):
  unsigned short* ctx16 = xb16;  // written by attn AFTER last read of xb16 (qkv gemm)
  float* gatef = (float*)qb;     // written by gate gemm AFTER attn reads q/k
  float* attnf = (float*)vb;     // written by out-proj gemm AFTER attn reads v, agg reads h16

  // 1) casts to bf16
  cast_f2b_kernel<<<(M * 768 / 4 + 255) / 256, 256, 0, stream>>>(x, xb16, M * 768 / 4);
  cast_f2b_kernel<<<(2304 * 768 / 4 + 255) / 256, 256, 0, stream>>>(ipw, wqkv, 2304 * 768 / 4);
  cast_f2b_kernel<<<(768 * 768 / 4 + 255) / 256, 256, 0, stream>>>(gcnW, wgcn, 768 * 768 / 4);
  cast_f2b_kernel<<<(768 * 768 / 4 + 255) / 256, 256, 0, stream>>>(opw, wout, 768 * 768 / 4);
  cast_f2b_kernel<<<(768 * 1536 / 4 + 255) / 256, 256, 0, stream>>>(gw, wgate, 768 * 1536 / 4);

  // 2) CSR build for GCN aggregation
  zero_i32_kernel<<<32, 256, 0, stream>>>(cnt, 8192);
  edge_count_kernel<<<(B * E) / 256, 256, 0, stream>>>(ei, cnt);
  scan_offs_kernel<<<8, 1024, 0, stream>>>(cnt, offs, cursor, dinv);
  edge_fill_kernel<<<(B * E) / 256, 256, 0, stream>>>(ei, cursor, elist);

  // 3) GEMMs + attention + aggregation
  gemm_bt<EPI_H><<<dim3(12, 64), 256, 0, stream>>>(xb16, wgcn, nullptr, 768,
                                                   (void*)h16, nullptr, nullptr);
  gemm_bt<EPI_QKV><<<dim3(36, 64), 256, 0, stream>>>(xb16, wqkv, ipb, 768,
                                                     (void*)qb, (void*)kb, (void*)vb);
  attn_kernel<<<dim3(16, 64), 256, 0, stream>>>(qb, kb, vb, ctx16);
  gcn_agg_kernel<<<8192, 256, 0, stream>>>(h16, ei, cnt, offs, elist, dinv, gcnb,
                                           gcnf, cat16);
  gemm_bt<EPI_ATTN><<<dim3(12, 64), 256, 0, stream>>>(ctx16, wout, opb, 768,
                                                      (void*)cat16, (void*)attnf, nullptr);
  gemm_bt<EPI_GATE><<<dim3(12, 64), 256, 0, stream>>>(cat16, wgate, gb, 1536,
                                                      nullptr, (void*)gatef, nullptr);

  // 4) gate blend + residual + LayerNorm
  ln_fuse_kernel<<<8192, 256, 0, stream>>>(gatef, gcnf, attnf, x, lng, lnb, out);
}